// Round 3
// baseline (1144.381 us; speedup 1.0000x reference)
//
#include <hip/hip_runtime.h>

#define NN 100000      // N_NODES
#define NE 3200000     // N_EDGES
#define NF 128         // N_F
#define NH 128         // HIDDEN
#define NP 8           // N_PRED
#define NG 64          // N_GRAPHS
#define NX 8           // XCDs

#define SCAN_B 1024
#define SCAN_NBLK 98   // ceil(100000/1024)

// wave-uniform XCD id (0..7) via HW_REG_XCC_ID (hwreg 20), bits [3:0]
__device__ __forceinline__ int xcc_id() {
    return (int)(__builtin_amdgcn_s_getreg((31u << 11) | 20u) & 7u);
}

// ---------------- init: zero per-XCD histograms, cnt, psum ----------------
__global__ void k_init(int* __restrict__ rcntX, float* __restrict__ degX,
                       float* __restrict__ cnt, float* __restrict__ psum) {
    int i = blockIdx.x * blockDim.x + threadIdx.x;
    if (i < NX * NN) { rcntX[i] = 0; degX[i] = 0.0f; }
    if (i < NG) cnt[i] = 0.0f;
    if (i < NG * NH) psum[i] = 0.0f;
}

// ---------------- fused XCD-local atomic pass ----------------
// slot[e] = fetch_inc(rcntX[xcd][row[e]]);  degX[xcd][col[e]] += w[e]
__global__ void k_atomic_pass(const int* __restrict__ ei, const float* __restrict__ w,
                              int* __restrict__ rcntX, float* __restrict__ degX,
                              unsigned* __restrict__ eslot) {
    int e = blockIdx.x * blockDim.x + threadIdx.x;
    if (e >= NE) return;
    int x = xcc_id();
    int r = ei[e], c = ei[NE + e];
    int s = __hip_atomic_fetch_add(&rcntX[x * NN + r], 1,
                                   __ATOMIC_RELAXED, __HIP_MEMORY_SCOPE_WORKGROUP);
    __hip_atomic_fetch_add(&degX[x * NN + c], w[e],
                           __ATOMIC_RELAXED, __HIP_MEMORY_SCOPE_WORKGROUP);
    eslot[e] = ((unsigned)x << 28) | (unsigned)s;
}

// ---------------- per-graph node counts ----------------
__global__ void k_cnt(const int* __restrict__ batch, float* __restrict__ cnt) {
    __shared__ float c[NG];
    int t = threadIdx.x;
    if (t < NG) c[t] = 0.0f;
    __syncthreads();
    int i = blockIdx.x * blockDim.x + t;
    if (i < NN) atomicAdd(&c[batch[i]], 1.0f);
    __syncthreads();
    if (t < NG && c[t] != 0.0f) atomicAdd(&cnt[t], c[t]);
}

// ---------------- reduce 8 XCD copies: dinv, rcnt total, per-XCD exclusive prefix ----------------
__global__ void k_xprefix(int* __restrict__ rcntX, const float* __restrict__ degX,
                          float* __restrict__ dinv, int* __restrict__ rcnt) {
    int r = blockIdx.x * blockDim.x + threadIdx.x;
    if (r >= NN) return;
    int acc = 0;
#pragma unroll
    for (int x = 0; x < NX; ++x) {
        int v = rcntX[x * NN + r];
        rcntX[x * NN + r] = acc;   // becomes exclusive prefix across XCDs
        acc += v;
    }
    rcnt[r] = acc;
    float d = 1.0f;                // self-loop weight
#pragma unroll
    for (int x = 0; x < NX; ++x) d += degX[x * NN + r];
    dinv[r] = rsqrtf(d);
}

// ---------------- scan pass 1: per-block exclusive prefix + block sums ----------------
__global__ __launch_bounds__(SCAN_B) void k_scan1(const int* __restrict__ rcnt,
                                                  int* __restrict__ px,
                                                  int* __restrict__ bsum) {
    __shared__ int s[SCAN_B];
    int t = threadIdx.x;
    int i = blockIdx.x * SCAN_B + t;
    int v = (i < NN) ? rcnt[i] : 0;
    s[t] = v;
    __syncthreads();
    for (int off = 1; off < SCAN_B; off <<= 1) {
        int x = (t >= off) ? s[t - off] : 0;
        __syncthreads();
        s[t] += x;
        __syncthreads();
    }
    px[i] = s[t] - v;
    if (t == SCAN_B - 1) bsum[blockIdx.x] = s[t];
}

// ---------------- scan pass 2 ----------------
__global__ void k_scan2(const int* __restrict__ bsum, int* __restrict__ bofs) {
    if (threadIdx.x == 0) {
        int acc = 0;
        for (int b = 0; b < SCAN_NBLK; ++b) { bofs[b] = acc; acc += bsum[b]; }
    }
}

// ---------------- scan pass 3: rowptr ----------------
__global__ void k_scan3(const int* __restrict__ px, const int* __restrict__ bofs,
                        int* __restrict__ rowptr) {
    int i = blockIdx.x * blockDim.x + threadIdx.x;
    if (i > NN) return;
    rowptr[i] = px[i] + bofs[i >> 10];
}

// ---------------- placement (no atomics): pack[pos] = (src, norm) ----------------
__global__ void k_place(const int* __restrict__ ei, const float* __restrict__ w,
                        const unsigned* __restrict__ eslot, const int* __restrict__ rowptr,
                        const int* __restrict__ rcntX, const float* __restrict__ dinv,
                        float2* __restrict__ pack) {
    int e = blockIdx.x * blockDim.x + threadIdx.x;
    if (e >= NE) return;
    int r = ei[e], c = ei[NE + e];
    unsigned u = eslot[e];
    int x = (int)(u >> 28);
    int s = (int)(u & 0x0FFFFFFFu);
    int pos = rowptr[r] + rcntX[x * NN + r] + s;
    pack[pos] = make_float2(__int_as_float(c), dinv[r] * w[e] * dinv[c]);
}

// ---------------- hop 1: Qa[n][g] = dinv^2*(batch[n]==g) + sum nrm*(batch[src]==g) ----------------
__global__ void k_q1_gather(const int* __restrict__ rowptr, const float2* __restrict__ pack,
                            const int* __restrict__ batch, const float* __restrict__ dinv,
                            float* __restrict__ Q) {
    int wid = (blockIdx.x * blockDim.x + threadIdx.x) >> 6;
    int lane = threadIdx.x & 63;
    if (wid >= NN) return;
    int beg = rowptr[wid], end = rowptr[wid + 1];
    float d = dinv[wid];
    float acc = (batch[wid] == lane) ? d * d : 0.0f;
    int e = beg;
    for (; e + 4 <= end; e += 4) {
        float2 p0 = pack[e], p1 = pack[e + 1], p2 = pack[e + 2], p3 = pack[e + 3];
        int b0 = batch[__float_as_int(p0.x)];
        int b1 = batch[__float_as_int(p1.x)];
        int b2 = batch[__float_as_int(p2.x)];
        int b3 = batch[__float_as_int(p3.x)];
        acc += (b0 == lane ? p0.y : 0.0f) + (b1 == lane ? p1.y : 0.0f)
             + (b2 == lane ? p2.y : 0.0f) + (b3 == lane ? p3.y : 0.0f);
    }
    for (; e < end; ++e) {
        float2 p = pack[e];
        acc += (batch[__float_as_int(p.x)] == lane) ? p.y : 0.0f;
    }
    Q[(wid << 6) + lane] = acc;
}

// ---------------- hops 2,3: Qout[n][g] = dinv^2*Qin[n][g] + sum nrm*Qin[src][g] ----------------
__global__ void k_hop_gather(const int* __restrict__ rowptr, const float2* __restrict__ pack,
                             const float* __restrict__ dinv, const float* __restrict__ Qin,
                             float* __restrict__ Qout) {
    int wid = (blockIdx.x * blockDim.x + threadIdx.x) >> 6;
    int lane = threadIdx.x & 63;
    if (wid >= NN) return;
    int beg = rowptr[wid], end = rowptr[wid + 1];
    float d = dinv[wid];
    float acc = d * d * Qin[(wid << 6) + lane];
    int e = beg;
    for (; e + 4 <= end; e += 4) {
        float2 p0 = pack[e], p1 = pack[e + 1], p2 = pack[e + 2], p3 = pack[e + 3];
        float q0 = Qin[(__float_as_int(p0.x) << 6) + lane];
        float q1 = Qin[(__float_as_int(p1.x) << 6) + lane];
        float q2 = Qin[(__float_as_int(p2.x) << 6) + lane];
        float q3 = Qin[(__float_as_int(p3.x) << 6) + lane];
        acc += p0.y * q0 + p1.y * q1 + p2.y * q2 + p3.y * q3;
    }
    for (; e < end; ++e) {
        float2 p = pack[e];
        acc += p.y * Qin[(__float_as_int(p.x) << 6) + lane];
    }
    Qout[(wid << 6) + lane] = acc;
}

// ---------------- psum[g][f] = sum_n Q3[n][g] * x[n][f] ----------------
__global__ __launch_bounds__(256) void k_pool(const float* __restrict__ Q,
                                              const float* __restrict__ x,
                                              float* __restrict__ psum) {
    __shared__ float q[NG];
    __shared__ float xv[NF];
    int t = threadIdx.x;
    int f0 = t & 31;
    int g8 = t >> 5;
    float acc[8][4] = {};
    for (int n = blockIdx.x; n < NN; n += gridDim.x) {
        if (t < 64) q[t] = Q[n * 64 + t];
        else if (t < 192) xv[t - 64] = x[n * 128 + (t - 64)];
        __syncthreads();
#pragma unroll
        for (int i = 0; i < 8; ++i) {
            float qv = q[g8 * 8 + i];
#pragma unroll
            for (int j = 0; j < 4; ++j)
                acc[i][j] += qv * xv[f0 + 32 * j];
        }
        __syncthreads();
    }
#pragma unroll
    for (int i = 0; i < 8; ++i)
#pragma unroll
        for (int j = 0; j < 4; ++j)
            atomicAdd(&psum[(g8 * 8 + i) * NF + f0 + 32 * j], acc[i][j]);
}

// ---------------- final: fold both linears ----------------
__global__ void k_final(const float* __restrict__ psum, const float* __restrict__ cnt,
                        const float* __restrict__ Wc, const float* __restrict__ bc,
                        const float* __restrict__ Wl, const float* __restrict__ bl,
                        float* __restrict__ out) {
    __shared__ float M[NP * NH];
    __shared__ float bias[NP];
    int t = threadIdx.x;
    for (int idx = t; idx < NP * NH; idx += 256) {
        int p = idx >> 7, f = idx & 127;
        float s = 0.0f;
        for (int h = 0; h < NH; ++h) s += Wl[p * NH + h] * Wc[h * NF + f];
        M[idx] = s;
    }
    if (t < NP) {
        float s = bl[t];
        for (int h = 0; h < NH; ++h) s += Wl[t * NH + h] * bc[h];
        bias[t] = s;
    }
    __syncthreads();
    for (int idx = t; idx < NG * NP; idx += 256) {
        int g = idx >> 3, p = idx & 7;
        float inv = 1.0f / fmaxf(cnt[g], 1.0f);
        float s = 0.0f;
        for (int f = 0; f < NF; ++f) s += psum[g * NF + f] * M[p * NH + f];
        out[idx] = s * inv + bias[p];
    }
}

extern "C" void kernel_launch(void* const* d_in, const int* in_sizes, int n_in,
                              void* d_out, int out_size, void* d_ws, size_t ws_size,
                              hipStream_t stream) {
    const float* x     = (const float*)d_in[0];
    const int*   ei    = (const int*)d_in[1];
    const float* ea    = (const float*)d_in[2];
    const int*   batch = (const int*)d_in[3];
    const float* Wc    = (const float*)d_in[4];
    const float* bc    = (const float*)d_in[5];
    const float* Wl    = (const float*)d_in[6];
    const float* bl    = (const float*)d_in[7];
    float* out = (float*)d_out;

    // ---- workspace layout (floats). Scratch region aliased under Qa:
    // scratch (rcntX, degX, rcnt, px, bsum, bofs, eslot) is dead before
    // k_q1_gather first writes Qa. Total ~77.6 MB.
    float* ws     = (float*)d_ws;
    float*  dinv   = ws;                          // NN
    int*    rowptr = (int*)(dinv + NN);           // NN+2 (padded even)
    float*  cnt    = (float*)(rowptr + NN + 2);   // NG
    float*  psum   = cnt + NG;                    // NG*NH
    float2* pack   = (float2*)(psum + NG * NH);   // NE float2
    float*  Qb     = (float*)(pack + NE);         // NN*64
    float*  Qa     = Qb + (size_t)NN * NG;        // NN*64  (overlaps scratch)
    // scratch aliases inside Qa region:
    int*      rcntX = (int*)Qa;                   // NX*NN
    float*    degX  = (float*)(rcntX + NX * NN);  // NX*NN
    int*      rcnt  = (int*)(degX + NX * NN);     // SCAN_NBLK*SCAN_B
    int*      px    = rcnt + SCAN_NBLK * SCAN_B;  // SCAN_NBLK*SCAN_B
    int*      bsum  = px + SCAN_NBLK * SCAN_B;    // SCAN_NBLK
    int*      bofs  = bsum + SCAN_NBLK;           // SCAN_NBLK
    unsigned* eslot = (unsigned*)(bofs + SCAN_NBLK); // NE

    const int B = 256;
    int gN  = (NN + B - 1) / B;                          // 391
    int gE  = (NE + B - 1) / B;                          // 12500
    int gX  = (NX * NN + B - 1) / B;                     // 3125
    int gW  = (int)(((long long)NN * 64 + B - 1) / B);   // 25000 (wave per node)

    k_init<<<gX, B, 0, stream>>>(rcntX, degX, cnt, psum);
    k_atomic_pass<<<gE, B, 0, stream>>>(ei, ea, rcntX, degX, eslot);
    k_cnt<<<gN, B, 0, stream>>>(batch, cnt);
    k_xprefix<<<gN, B, 0, stream>>>(rcntX, degX, dinv, rcnt);

    k_scan1<<<SCAN_NBLK, SCAN_B, 0, stream>>>(rcnt, px, bsum);
    k_scan2<<<1, 64, 0, stream>>>(bsum, bofs);
    k_scan3<<<(NN + 1 + SCAN_B - 1) / SCAN_B, SCAN_B, 0, stream>>>(px, bofs, rowptr);
    k_place<<<gE, B, 0, stream>>>(ei, ea, eslot, rowptr, rcntX, dinv, pack);

    k_q1_gather<<<gW, B, 0, stream>>>(rowptr, pack, batch, dinv, Qa);
    k_hop_gather<<<gW, B, 0, stream>>>(rowptr, pack, dinv, Qa, Qb);
    k_hop_gather<<<gW, B, 0, stream>>>(rowptr, pack, dinv, Qb, Qa);

    k_pool<<<256, B, 0, stream>>>(Qa, x, psum);
    k_final<<<1, B, 0, stream>>>(psum, cnt, Wc, bc, Wl, bl, out);
}